// Round 5
// baseline (303.164 us; speedup 1.0000x reference)
//
#include <hip/hip_runtime.h>
#include <math.h>

#define BB 256
#define NN 512
#define DD 6
#define F_IN 62
#define HH 128
#define ND 7
#define TOTAL (BB*NN)
#define BSTR 136   // bufB row stride in bf16 elems (272 B: 16B-aligned rows, bank-spreading)

typedef __bf16 bf16x8 __attribute__((ext_vector_type(8)));
typedef float f32x4 __attribute__((ext_vector_type(4)));

__device__ __forceinline__ unsigned short f2bf(float f) {
    unsigned u = __builtin_bit_cast(unsigned, f);
    u = (u + 0x7FFFu + ((u >> 16) & 1u)) >> 16;
    return (unsigned short)u;
}
__device__ __forceinline__ float lo2f(unsigned x) { return __builtin_bit_cast(float, x << 16); }
__device__ __forceinline__ float hi2f(unsigned x) { return __builtin_bit_cast(float, x & 0xFFFF0000u); }

__device__ __forceinline__ uint4 pack8(const float* s) {
    uint4 r;
    r.x = (unsigned)f2bf(s[0]) | ((unsigned)f2bf(s[1]) << 16);
    r.y = (unsigned)f2bf(s[2]) | ((unsigned)f2bf(s[3]) << 16);
    r.z = (unsigned)f2bf(s[4]) | ((unsigned)f2bf(s[5]) << 16);
    r.w = (unsigned)f2bf(s[6]) | ((unsigned)f2bf(s[7]) << 16);
    return r;
}
__device__ __forceinline__ void unpack_add(float* s, uint4 q) {
    s[0] += lo2f(q.x); s[1] += hi2f(q.x); s[2] += lo2f(q.y); s[3] += hi2f(q.y);
    s[4] += lo2f(q.z); s[5] += hi2f(q.z); s[6] += lo2f(q.w); s[7] += hi2f(q.w);
}
__device__ __forceinline__ void unpack_max(float* s, uint4 q) {
    s[0] = fmaxf(s[0], lo2f(q.x)); s[1] = fmaxf(s[1], hi2f(q.x));
    s[2] = fmaxf(s[2], lo2f(q.y)); s[3] = fmaxf(s[3], hi2f(q.y));
    s[4] = fmaxf(s[4], lo2f(q.z)); s[5] = fmaxf(s[5], hi2f(q.z));
    s[6] = fmaxf(s[6], lo2f(q.w)); s[7] = fmaxf(s[7], hi2f(q.w));
}

// ---------------- prep: W [ND][F][HH] f32 -> WT [ND][HH][K] bf16 (K-contig, pad) ----------------

__global__ void k_prep_wt(const float* __restrict__ W, unsigned short* __restrict__ WT,
                          int F, int K) {
    int n = blockIdx.x;   // 0..127
    int d = blockIdx.y;   // 0..6
    for (int k = threadIdx.x; k < K; k += 64) {
        float v = (k < F) ? W[((size_t)d * F + k) * HH + n] : 0.f;
        WT[((size_t)d * HH + n) * K + k] = f2bf(v);
    }
}

// ---------------- fused per-batch pipeline: conv1 -> pool1 -> conv2 -> pool2+sum ----------------
// 1 block = 1 batch. 512 threads = 8 waves. Dynamic LDS ~159.5 KB.
// LDS layout (bytes):
//   0        bufB  [512][BSTR] bf16 (139264)  h1 then h2, 16B-chunk XOR-swizzled per row
//   139264   sT    [64][128]  bf16 (16384)    per-tile A staging + epilogue staging; f32[8][512] in pool2
//   155648   eL    [512][6]   short (6144)
//   161792   ordL  [640]      short (1280)    degree-sorted, 16-padded node order (-1 = pad)
//   163072   dgrp  [40]       int   (160)     degree of each 16-row group
//   163232   scnt  [8] uint, 163264 sbase [8] uint  -> total 163296

__global__ __launch_bounds__(512, 2)
void k_fused(const float* __restrict__ a, const int* __restrict__ e,
             const unsigned short* __restrict__ WT0, const float* __restrict__ b0,
             const unsigned short* __restrict__ WT1, const float* __restrict__ b1,
             unsigned short* __restrict__ pbuf, float* __restrict__ out) {
    extern __shared__ char smem[];
    unsigned short* bufB = (unsigned short*)smem;
    unsigned short* sT   = (unsigned short*)(smem + 139264);
    float*          sTf  = (float*)sT;
    short*          eL   = (short*)(smem + 155648);
    short*          ordL = (short*)(smem + 161792);
    int*            dgrp = (int*)(smem + 163072);
    unsigned*       scnt = (unsigned*)(smem + 163232);
    unsigned*       sbase= (unsigned*)(smem + 163264);

    const int t = threadIdx.x;
    const int b = blockIdx.x;
    const int l = t & 63;
    const int w = t >> 6;          // wave 0..7: owns output cols [16w, 16w+16)
    const int lr = l & 15;
    const int lq = l >> 4;

    // ---- stage edges, counting-sort nodes by degree with 16-aligned buckets ----
    for (int i = t; i < NN * DD; i += 512) eL[i] = (short)e[b * NN * DD + i];
    if (t < 8) scnt[t] = 0u;
    for (int i = t; i < 640; i += 512) ordL[i] = -1;
    __syncthreads();
    int dg = 0;
#pragma unroll
    for (int j = 0; j < DD; ++j) dg += (eL[t * DD + j] >= 0) ? 1 : 0;
    unsigned rk = atomicAdd(&scnt[dg], 1u);
    __syncthreads();
    if (t == 0) {
        unsigned acc = 0;
        for (int k = 0; k < ND; ++k) { sbase[k] = acc; acc += (scnt[k] + 15u) & ~15u; }
        sbase[7] = acc;
        for (int k = 0; k < ND; ++k)
            for (unsigned g = sbase[k] >> 4; g < (sbase[k + 1] >> 4); ++g) dgrp[g] = k;
        for (unsigned g = acc >> 4; g < 40u; ++g) dgrp[g] = 0;
    }
    __syncthreads();
    ordL[sbase[dg] + rk] = (short)t;
    __syncthreads();
    const int ntot = (int)sbase[7];
    const int NT = (ntot + 63) >> 6;

    // ================= conv1: h1 = sigmoid((a_self+sum nbr) @ W0[deg] + b0[deg]) -> bufB =================
    for (int tile = 0; tile < NT; ++tile) {
        // phase1: gather-sum raw f32 rows of `a` (62 cols), pack bf16 into sT [64][64] swizzled
        {
            const int n = t >> 3, kb = t & 7;
            const int v = (int)ordL[tile * 64 + n];
            float s[8] = {0.f, 0.f, 0.f, 0.f, 0.f, 0.f, 0.f, 0.f};
            if (v >= 0) {
                const int nc2 = (kb < 7) ? 4 : 3;
                const float* rs = a + ((size_t)(b * NN + v)) * F_IN + kb * 8;
#pragma unroll 4
                for (int q = 0; q < nc2; ++q) { float2 z = *(const float2*)(rs + 2 * q); s[2 * q] += z.x; s[2 * q + 1] += z.y; }
#pragma unroll
                for (int j = 0; j < DD; ++j) {
                    int idx = (int)eL[v * DD + j];
                    if (idx >= 0) {
                        const float* rn = a + ((size_t)(b * NN + idx)) * F_IN + kb * 8;
#pragma unroll 4
                        for (int q = 0; q < nc2; ++q) { float2 z = *(const float2*)(rn + 2 * q); s[2 * q] += z.x; s[2 * q + 1] += z.y; }
                    }
                }
            }
            *(uint4*)(sT + n * 64 + ((kb ^ (n & 7)) * 8)) = pack8(s);
        }
        __syncthreads();
        // MFMA: per-16-row-group degree-pure; B frags per group
        f32x4 acc[4];
#pragma unroll
        for (int mb = 0; mb < 4; ++mb) {
            const int d = dgrp[tile * 4 + mb];
            const unsigned short* wp = WT0 + ((size_t)(d * HH + 16 * w + lr)) * 64 + lq * 8;
            const int nrow = mb * 16 + lr;
            f32x4 z = {0.f, 0.f, 0.f, 0.f};
            bf16x8 af0 = *(const bf16x8*)(sT + nrow * 64 + (((0 + lq) ^ (lr & 7)) * 8));
            bf16x8 bf0 = *(const bf16x8*)(wp);
            z = __builtin_amdgcn_mfma_f32_16x16x32_bf16(af0, bf0, z, 0, 0, 0);
            bf16x8 af1 = *(const bf16x8*)(sT + nrow * 64 + (((4 + lq) ^ (lr & 7)) * 8));
            bf16x8 bf1 = *(const bf16x8*)(wp + 32);
            z = __builtin_amdgcn_mfma_f32_16x16x32_bf16(af1, bf1, z, 0, 0, 0);
            acc[mb] = z;
        }
        __syncthreads();   // sT A-reads complete
        // epilogue: sigmoid -> sT [64][128] swizzled
#pragma unroll
        for (int mb = 0; mb < 4; ++mb) {
            const int d = dgrp[tile * 4 + mb];
            const int c = 16 * w + lr;
            const float bv = b0[d * HH + c];
#pragma unroll
            for (int r2 = 0; r2 < 4; ++r2) {
                const int n = mb * 16 + lq * 4 + r2;
                float zz = 1.f / (1.f + __expf(-(acc[mb][r2] + bv)));
                sT[n * 128 + (((c >> 3) ^ (n & 7)) * 8) + (c & 7)] = f2bf(zz);
            }
        }
        __syncthreads();
        // scatter-copy sT rows -> bufB natural rows (re-swizzle)
        for (int i = t; i < 1024; i += 512) {
            const int n = i >> 4, pc = i & 15;
            const int v = (int)ordL[tile * 64 + n];
            if (v >= 0) {
                uint4 q = *(const uint4*)(sT + n * 128 + pc * 8);
                const int c = pc ^ (n & 7);
                *(uint4*)(bufB + v * BSTR + ((c ^ (v & 7)) * 8)) = q;
            }
        }
        __syncthreads();
    }

    // ================= pool1: p1[v] = max(h1[v], h1[nbrs]) -> GLOBAL pbuf =================
    for (int ck = 0; ck < 16; ++ck) {
        float m[8];
        {
            uint4 q = *(const uint4*)(bufB + t * BSTR + ((ck ^ (t & 7)) * 8));
            m[0] = lo2f(q.x); m[1] = hi2f(q.x); m[2] = lo2f(q.y); m[3] = hi2f(q.y);
            m[4] = lo2f(q.z); m[5] = hi2f(q.z); m[6] = lo2f(q.w); m[7] = hi2f(q.w);
        }
#pragma unroll
        for (int j = 0; j < DD; ++j) {
            int idx = (int)eL[t * DD + j];
            if (idx >= 0) unpack_max(m, *(const uint4*)(bufB + idx * BSTR + ((ck ^ (idx & 7)) * 8)));
        }
        *(uint4*)(pbuf + ((size_t)(b * NN + t)) * HH + ck * 8) = pack8(m);
    }
    __syncthreads();   // drains vmcnt: pbuf visible to whole block via L2

    // ================= conv2: h2 = sigmoid((p1_self+sum nbr) @ W1[deg] + b1[deg]) -> bufB =================
    for (int tile = 0; tile < NT; ++tile) {
        for (int uu = t; uu < 1024; uu += 512) {
            const int n = uu >> 4, kb = uu & 15;
            const int v = (int)ordL[tile * 64 + n];
            float s[8] = {0.f, 0.f, 0.f, 0.f, 0.f, 0.f, 0.f, 0.f};
            if (v >= 0) {
                const unsigned short* base = pbuf + (size_t)b * NN * HH;
                unpack_add(s, *(const uint4*)(base + (size_t)v * HH + kb * 8));
#pragma unroll
                for (int j = 0; j < DD; ++j) {
                    int idx = (int)eL[v * DD + j];
                    if (idx >= 0) unpack_add(s, *(const uint4*)(base + (size_t)idx * HH + kb * 8));
                }
            }
            *(uint4*)(sT + n * 128 + ((kb ^ (n & 7)) * 8)) = pack8(s);
        }
        __syncthreads();
        f32x4 acc[4];
#pragma unroll
        for (int mb = 0; mb < 4; ++mb) {
            const int d = dgrp[tile * 4 + mb];
            const unsigned short* wp = WT1 + ((size_t)(d * HH + 16 * w + lr)) * 128 + lq * 8;
            const int nrow = mb * 16 + lr;
            f32x4 z = {0.f, 0.f, 0.f, 0.f};
#pragma unroll
            for (int kk = 0; kk < 4; ++kk) {
                bf16x8 af = *(const bf16x8*)(sT + nrow * 128 + (((kk * 4 + lq) ^ (lr & 7)) * 8));
                bf16x8 bfr = *(const bf16x8*)(wp + kk * 32);
                z = __builtin_amdgcn_mfma_f32_16x16x32_bf16(af, bfr, z, 0, 0, 0);
            }
            acc[mb] = z;
        }
        __syncthreads();
#pragma unroll
        for (int mb = 0; mb < 4; ++mb) {
            const int d = dgrp[tile * 4 + mb];
            const int c = 16 * w + lr;
            const float bv = b1[d * HH + c];
#pragma unroll
            for (int r2 = 0; r2 < 4; ++r2) {
                const int n = mb * 16 + lq * 4 + r2;
                float zz = 1.f / (1.f + __expf(-(acc[mb][r2] + bv)));
                sT[n * 128 + (((c >> 3) ^ (n & 7)) * 8) + (c & 7)] = f2bf(zz);
            }
        }
        __syncthreads();
        for (int i = t; i < 1024; i += 512) {
            const int n = i >> 4, pc = i & 15;
            const int v = (int)ordL[tile * 64 + n];
            if (v >= 0) {
                uint4 q = *(const uint4*)(sT + n * 128 + pc * 8);
                const int c = pc ^ (n & 7);
                *(uint4*)(bufB + v * BSTR + ((c ^ (v & 7)) * 8)) = q;
            }
        }
        __syncthreads();
    }

    // ================= pool2 + per-batch sum -> out[b][0..127] =================
    for (int ck = 0; ck < 16; ++ck) {
        float m[8];
        {
            uint4 q = *(const uint4*)(bufB + t * BSTR + ((ck ^ (t & 7)) * 8));
            m[0] = lo2f(q.x); m[1] = hi2f(q.x); m[2] = lo2f(q.y); m[3] = hi2f(q.y);
            m[4] = lo2f(q.z); m[5] = hi2f(q.z); m[6] = lo2f(q.w); m[7] = hi2f(q.w);
        }
#pragma unroll
        for (int j = 0; j < DD; ++j) {
            int idx = (int)eL[t * DD + j];
            if (idx >= 0) unpack_max(m, *(const uint4*)(bufB + idx * BSTR + ((ck ^ (idx & 7)) * 8)));
        }
        // stage column-major f32 [8][512] into sT region, then wave-reduce
#pragma unroll
        for (int q = 0; q < 8; ++q) sTf[q * 512 + t] = m[q];
        __syncthreads();
        float partial = 0.f;
#pragma unroll
        for (int i = 0; i < 8; ++i) partial += sTf[w * 512 + l + 64 * i];
#pragma unroll
        for (int off = 32; off >= 1; off >>= 1) partial += __shfl_xor(partial, off);
        if (l == 0) out[b * HH + ck * 8 + w] = partial;
        __syncthreads();
    }
}

// ---------------- launcher ----------------

extern "C" void kernel_launch(void* const* d_in, const int* in_sizes, int n_in,
                              void* d_out, int out_size, void* d_ws, size_t ws_size,
                              hipStream_t stream) {
    const float* a  = (const float*)d_in[0];
    const int*   e  = (const int*)d_in[1];
    const float* W0 = (const float*)d_in[2];
    const float* b0 = (const float*)d_in[3];
    const float* W1 = (const float*)d_in[4];
    const float* b1 = (const float*)d_in[5];
    float* out = (float*)d_out;

    char* ws = (char*)d_ws;
    unsigned short* pbuf = (unsigned short*)ws;                        // 32 MB
    unsigned short* WT0  = (unsigned short*)(ws + (size_t)TOTAL * HH * 2);
    unsigned short* WT1  = WT0 + (size_t)ND * HH * 64;

    hipLaunchKernelGGL(k_prep_wt, dim3(HH, ND), dim3(64), 0, stream, W0, WT0, F_IN, 64);
    hipLaunchKernelGGL(k_prep_wt, dim3(HH, ND), dim3(64), 0, stream, W1, WT1, HH, HH);

    (void)hipFuncSetAttribute((const void*)k_fused,
                              hipFuncAttributeMaxDynamicSharedMemorySize, 163296);
    hipLaunchKernelGGL(k_fused, dim3(BB), dim3(512), 163296, stream,
                       a, e, WT0, b0, WT1, b1, pbuf, out);
}

// Round 6
// 146.460 us; speedup vs baseline: 2.0699x; 2.0699x over previous
//
#include <hip/hip_runtime.h>
#include <math.h>

#define BB 256
#define NN 512
#define DD 6
#define F_IN 62
#define HH 128
#define ND 7
#define TOTAL (BB*NN)   // 131072
#define OPB 640         // padded order slots per batch (512 + 7*15 max pad, rounded)
#define GPB 40          // 16-row groups per batch (OPB/16)
#define TPB 10          // max 64-row tiles per batch (OPB/64)

typedef __bf16 bf16x8 __attribute__((ext_vector_type(8)));
typedef float f32x4 __attribute__((ext_vector_type(4)));

__device__ __forceinline__ unsigned short f2bf(float f) {
    unsigned u = __builtin_bit_cast(unsigned, f);
    u = (u + 0x7FFFu + ((u >> 16) & 1u)) >> 16;
    return (unsigned short)u;
}
__device__ __forceinline__ float lo2f(unsigned x) { return __builtin_bit_cast(float, x << 16); }
__device__ __forceinline__ float hi2f(unsigned x) { return __builtin_bit_cast(float, x & 0xFFFF0000u); }

// ---------------- per-batch counting sort by degree, buckets padded to 16 ----------------
// order[b][i] = batch-local node id or -1 (pad); dgrp[b][g] = degree of 16-row group g;
// ntiles[b] = number of 64-row tiles containing any real node.

__global__ __launch_bounds__(512) void k_sort16(const int* __restrict__ e,
                                                int* __restrict__ order,
                                                int* __restrict__ dgrp,
                                                int* __restrict__ ntiles) {
    __shared__ unsigned int scnt[ND];
    __shared__ unsigned int sbase[ND + 1];
    const int b = blockIdx.x;
    const int t = threadIdx.x;
    if (t < ND) scnt[t] = 0u;
    for (int i = t; i < OPB; i += 512) order[b * OPB + i] = -1;
    __syncthreads();
    int d = 0;
#pragma unroll
    for (int j = 0; j < DD; ++j) d += (e[(b * NN + t) * DD + j] >= 0) ? 1 : 0;
    unsigned rk = atomicAdd(&scnt[d], 1u);
    __syncthreads();
    if (t == 0) {
        unsigned acc = 0;
        for (int k = 0; k < ND; ++k) { sbase[k] = acc; acc += (scnt[k] + 15u) & ~15u; }
        sbase[ND] = acc;
        for (int k = 0; k < ND; ++k)
            for (unsigned g = sbase[k] >> 4; g < (sbase[k + 1] >> 4); ++g)
                dgrp[b * GPB + g] = k;
        for (unsigned g = acc >> 4; g < GPB; ++g) dgrp[b * GPB + g] = 0;
        ntiles[b] = (int)((acc + 63u) >> 6);
    }
    __syncthreads();
    order[b * OPB + sbase[d] + rk] = t;
}

// ---------------- prep: a (f32 [TOTAL][62]) -> bf16 [TOTAL][64], zero-pad ----------------

__global__ __launch_bounds__(256) void k_prep_a(const float* __restrict__ a,
                                                unsigned short* __restrict__ Ap) {
    int u = blockIdx.x * 256 + threadIdx.x;   // unit = 8 cols
    int r = u >> 3;
    int c0 = (u & 7) * 8;
    unsigned short h[8];
#pragma unroll
    for (int i = 0; i < 8; ++i) {
        int c = c0 + i;
        h[i] = (c < F_IN) ? f2bf(a[(size_t)r * F_IN + c]) : (unsigned short)0;
    }
    uint4 p;
    p.x = (unsigned)h[0] | ((unsigned)h[1] << 16);
    p.y = (unsigned)h[2] | ((unsigned)h[3] << 16);
    p.z = (unsigned)h[4] | ((unsigned)h[5] << 16);
    p.w = (unsigned)h[6] | ((unsigned)h[7] << 16);
    *(uint4*)&Ap[(size_t)r * 64 + c0] = p;
}

// ---------------- prep: W [ND][F][HH] f32 -> WT [ND][HH][K] bf16 (K-contig, pad) ----------------

__global__ void k_prep_wt(const float* __restrict__ W, unsigned short* __restrict__ WT,
                          int F, int K) {
    int n = blockIdx.x;   // 0..127
    int d = blockIdx.y;   // 0..6
    for (int k = threadIdx.x; k < K; k += 64) {
        float v = (k < F) ? W[((size_t)d * F + k) * HH + n] : 0.f;
        WT[((size_t)d * HH + n) * K + k] = f2bf(v);
    }
}

// ---------------- conv via MFMA, 16-row degree-pure groups ----------------
// Xp: bf16 [TOTAL][K], WT: bf16 [ND][HH][K], Y: bf16 [TOTAL][HH]
// Grid = BB*TPB, XCD-swizzled: all tiles of a batch on one XCD. Early-exit on pad tiles.

template<int KB>   // KB = K/8 (8 for conv1 K=64, 16 for conv2 K=128)
__global__ __launch_bounds__(256, 3)
void k_conv_mfma(const unsigned short* __restrict__ Xp,
                 const int* __restrict__ e,
                 const unsigned short* __restrict__ WT,
                 const float* __restrict__ bias,
                 const int* __restrict__ order,
                 const int* __restrict__ dgrp,
                 const int* __restrict__ ntiles,
                 unsigned short* __restrict__ Y) {
    constexpr int K = KB * 8;
    constexpr int LOGKB = (KB == 16) ? 4 : 3;
    __shared__ unsigned short sP[64 * 128];   // gather tile (swizzled) / epilogue staging
    __shared__ int vT[64];
    __shared__ int eT[64 * DD];

    const int t = threadIdx.x;
    const int l = t & 63;
    const int w = t >> 6;

    // XCD-aware mapping: xcd = bi&7; batches grouped so one batch's tiles share an XCD.
    const int bi = blockIdx.x;
    const int x8 = bi & 7;
    const int j = bi >> 3;
    const int batch = x8 + 8 * (j / TPB);
    const int tile = j % TPB;
    if (tile >= ntiles[batch]) return;

    if (t < 64) vT[t] = order[batch * OPB + tile * 64 + t];
    __syncthreads();
    for (int i = t; i < 64 * DD; i += 256) {
        int v = vT[i / DD];
        if (v >= 0) eT[i] = e[((size_t)batch * NN + v) * DD + (i % DD)];
    }
    __syncthreads();

    // phase 1: gather-sum (f32) -> bf16 -> swizzled LDS [n][kb ^ (n&7)] units of 8
    for (int u = t; u < 64 * KB; u += 256) {
        const int kb = u & (KB - 1);
        const int n = u >> LOGKB;
        const int v = vT[n];
        float s[8] = {0.f, 0.f, 0.f, 0.f, 0.f, 0.f, 0.f, 0.f};
        if (v >= 0) {
            const unsigned short* base = Xp + (size_t)batch * NN * K;
            uint4 p = *(const uint4*)(base + (size_t)v * K + kb * 8);
            s[0] = lo2f(p.x); s[1] = hi2f(p.x); s[2] = lo2f(p.y); s[3] = hi2f(p.y);
            s[4] = lo2f(p.z); s[5] = hi2f(p.z); s[6] = lo2f(p.w); s[7] = hi2f(p.w);
#pragma unroll
            for (int jj = 0; jj < DD; ++jj) {
                int idx = eT[n * DD + jj];
                if (idx >= 0) {
                    uint4 q = *(const uint4*)(base + (size_t)idx * K + kb * 8);
                    s[0] += lo2f(q.x); s[1] += hi2f(q.x); s[2] += lo2f(q.y); s[3] += hi2f(q.y);
                    s[4] += lo2f(q.z); s[5] += hi2f(q.z); s[6] += lo2f(q.w); s[7] += hi2f(q.w);
                }
            }
        }
        uint4 r;
        r.x = (unsigned)f2bf(s[0]) | ((unsigned)f2bf(s[1]) << 16);
        r.y = (unsigned)f2bf(s[2]) | ((unsigned)f2bf(s[3]) << 16);
        r.z = (unsigned)f2bf(s[4]) | ((unsigned)f2bf(s[5]) << 16);
        r.w = (unsigned)f2bf(s[6]) | ((unsigned)f2bf(s[7]) << 16);
        const int kbs = kb ^ (n & 7);
        *(uint4*)&sP[(n * KB + kbs) * 8] = r;
    }
    __syncthreads();

    const int lr = l & 15;
    const int lq = l >> 4;

    int dg[4];
#pragma unroll
    for (int mb = 0; mb < 4; ++mb) dg[mb] = dgrp[batch * GPB + tile * 4 + mb];

    // MFMA: each 16-row group degree-pure; reload B frags only on degree change (wave-uniform)
    bf16x8 bf[K / 32][2];
    f32x4 acc[4][2];
    int dprev = -1;
#pragma unroll
    for (int mb = 0; mb < 4; ++mb) {
        const int d = dg[mb];
        if (d != dprev) {
#pragma unroll
            for (int kk = 0; kk < K / 32; ++kk)
#pragma unroll
                for (int nb = 0; nb < 2; ++nb) {
                    int ncol = w * 32 + nb * 16 + lr;
                    int krow = kk * 32 + lq * 8;
                    bf[kk][nb] = *(const bf16x8*)(WT + ((size_t)d * HH + ncol) * K + krow);
                }
            dprev = d;
        }
        f32x4 z0 = {0.f, 0.f, 0.f, 0.f};
        f32x4 z1 = {0.f, 0.f, 0.f, 0.f};
        const int nrow = mb * 16 + lr;
#pragma unroll
        for (int kk = 0; kk < K / 32; ++kk) {
            int kbp = kk * 4 + lq;
            int kbs = kbp ^ (nrow & 7);
            bf16x8 af = *(const bf16x8*)&sP[(nrow * KB + kbs) * 8];
            z0 = __builtin_amdgcn_mfma_f32_16x16x32_bf16(af, bf[kk][0], z0, 0, 0, 0);
            z1 = __builtin_amdgcn_mfma_f32_16x16x32_bf16(af, bf[kk][1], z1, 0, 0, 0);
        }
        acc[mb][0] = z0;
        acc[mb][1] = z1;
    }

    __syncthreads();   // all A-frag reads done; reuse sP as [64][HH] staging
#pragma unroll
    for (int mb = 0; mb < 4; ++mb) {
        const int d = dg[mb];
#pragma unroll
        for (int nb = 0; nb < 2; ++nb) {
            int col = w * 32 + nb * 16 + lr;
            float bv = bias[d * HH + col];
#pragma unroll
            for (int r = 0; r < 4; ++r) {
                int n = mb * 16 + lq * 4 + r;
                float z = 1.f / (1.f + __expf(-(acc[mb][nb][r] + bv)));
                sP[n * HH + col] = f2bf(z);
            }
        }
    }
    __syncthreads();
    for (int u = t; u < 1024; u += 256) {
        int n = u >> 4;
        int c8 = (u & 15) * 8;
        int v = vT[n];
        if (v >= 0) {
            uint4 p = *(const uint4*)&sP[n * HH + c8];
            *(uint4*)&Y[((size_t)batch * NN + v) * HH + c8] = p;
        }
    }
}

// ---------------- pool: P[v] = max(X[v], X[neighbors]) on bf16 rows ----------------
// Grid = 8192 = 32 blocks x 256 batches, XCD-swizzled.

__global__ __launch_bounds__(256) void k_pool_bf(const unsigned short* __restrict__ X,
                                                 const int* __restrict__ e,
                                                 unsigned short* __restrict__ P) {
    const int t = threadIdx.x;
    const int bi = blockIdx.x;
    const int x8 = bi & 7;
    const int j = bi >> 3;
    const int batch = x8 + 8 * (j >> 5);
    const int sub = j & 31;
    const int u = batch * NN + sub * 16 + (t >> 4);
    const int c8 = (t & 15) * 8;
    const int nbase = u & ~(NN - 1);
    float m[8];
    {
        uint4 p = *(const uint4*)(X + (size_t)u * HH + c8);
        m[0] = lo2f(p.x); m[1] = hi2f(p.x); m[2] = lo2f(p.y); m[3] = hi2f(p.y);
        m[4] = lo2f(p.z); m[5] = hi2f(p.z); m[6] = lo2f(p.w); m[7] = hi2f(p.w);
    }
#pragma unroll
    for (int jj = 0; jj < DD; ++jj) {
        int idx = e[u * DD + jj];
        if (idx >= 0) {
            uint4 p = *(const uint4*)(X + (size_t)(nbase + idx) * HH + c8);
            m[0] = fmaxf(m[0], lo2f(p.x)); m[1] = fmaxf(m[1], hi2f(p.x));
            m[2] = fmaxf(m[2], lo2f(p.y)); m[3] = fmaxf(m[3], hi2f(p.y));
            m[4] = fmaxf(m[4], lo2f(p.z)); m[5] = fmaxf(m[5], hi2f(p.z));
            m[6] = fmaxf(m[6], lo2f(p.w)); m[7] = fmaxf(m[7], hi2f(p.w));
        }
    }
    uint4 r;
    r.x = (unsigned)f2bf(m[0]) | ((unsigned)f2bf(m[1]) << 16);
    r.y = (unsigned)f2bf(m[2]) | ((unsigned)f2bf(m[3]) << 16);
    r.z = (unsigned)f2bf(m[4]) | ((unsigned)f2bf(m[5]) << 16);
    r.w = (unsigned)f2bf(m[6]) | ((unsigned)f2bf(m[7]) << 16);
    *(uint4*)&P[(size_t)u * HH + c8] = r;
}

// ---------------- final: pool + partial sum (8 blocks per batch, XCD-swizzled) ----------------

__global__ __launch_bounds__(256) void k_pool_sum_part(const unsigned short* __restrict__ X,
                                                       const int* __restrict__ e,
                                                       float* __restrict__ partial) {
    __shared__ float red[16][HH + 4];
    const int t = threadIdx.x;
    const int bi = blockIdx.x;
    const int x8 = bi & 7;
    const int j = bi >> 3;
    const int b = x8 + 8 * (j >> 3);
    const int chunk = j & 7;
    const int slot = t >> 4;
    const int c8 = (t & 15) * 8;
    float acc[8];
#pragma unroll
    for (int i = 0; i < 8; ++i) acc[i] = 0.f;

    for (int n = chunk * 64 + slot; n < chunk * 64 + 64; n += 16) {
        int u = b * NN + n;
        float m[8];
        uint4 p = *(const uint4*)(X + (size_t)u * HH + c8);
        m[0] = lo2f(p.x); m[1] = hi2f(p.x); m[2] = lo2f(p.y); m[3] = hi2f(p.y);
        m[4] = lo2f(p.z); m[5] = hi2f(p.z); m[6] = lo2f(p.w); m[7] = hi2f(p.w);
#pragma unroll
        for (int jj = 0; jj < DD; ++jj) {
            int idx = e[u * DD + jj];
            if (idx >= 0) {
                uint4 q = *(const uint4*)(X + (size_t)(b * NN + idx) * HH + c8);
                m[0] = fmaxf(m[0], lo2f(q.x)); m[1] = fmaxf(m[1], hi2f(q.x));
                m[2] = fmaxf(m[2], lo2f(q.y)); m[3] = fmaxf(m[3], hi2f(q.y));
                m[4] = fmaxf(m[4], lo2f(q.z)); m[5] = fmaxf(m[5], hi2f(q.z));
                m[6] = fmaxf(m[6], lo2f(q.w)); m[7] = fmaxf(m[7], hi2f(q.w));
            }
        }
#pragma unroll
        for (int i = 0; i < 8; ++i) acc[i] += m[i];
    }
#pragma unroll
    for (int i = 0; i < 8; ++i) red[slot][c8 + i] = acc[i];
    __syncthreads();
    if (t < HH) {
        float s = 0.f;
#pragma unroll
        for (int k = 0; k < 16; ++k) s += red[k][t];
        partial[(size_t)(b * 8 + chunk) * HH + t] = s;
    }
}

// ---------------- final reduce: out[b][c] = sum of 8 partials (deterministic) ----------------

__global__ __launch_bounds__(256) void k_sum_final(const float* __restrict__ partial,
                                                   float* __restrict__ out) {
    int g = blockIdx.x * 256 + threadIdx.x;   // b*HH + c, 32768 total
    int b = g >> 7;
    int c = g & 127;
    float s = 0.f;
#pragma unroll
    for (int k = 0; k < 8; ++k) s += partial[(size_t)(b * 8 + k) * HH + c];
    out[g] = s;
}

// ---------------- launcher ----------------

extern "C" void kernel_launch(void* const* d_in, const int* in_sizes, int n_in,
                              void* d_out, int out_size, void* d_ws, size_t ws_size,
                              hipStream_t stream) {
    const float* a  = (const float*)d_in[0];
    const int*   e  = (const int*)d_in[1];
    const float* W0 = (const float*)d_in[2];
    const float* b0 = (const float*)d_in[3];
    const float* W1 = (const float*)d_in[4];
    const float* b1 = (const float*)d_in[5];
    float* out = (float*)d_out;

    char* ws = (char*)d_ws;
    const size_t XB = (size_t)TOTAL * HH * 2;    // 32 MB bf16
    unsigned short* xbuf = (unsigned short*)ws;
    unsigned short* pbuf = (unsigned short*)(ws + XB);
    unsigned short* Ap   = (unsigned short*)(ws + 2 * XB);                 // 16 MB
    float* partial = (float*)Ap;   // reuse: Ap dead after conv1; partial used at the end (1 MB)
    unsigned short* WT0  = (unsigned short*)(ws + 2 * XB + (size_t)TOTAL * 64 * 2);
    unsigned short* WT1  = WT0 + (size_t)ND * HH * 64;
    char* ip = (char*)(WT1 + (size_t)ND * HH * 128);
    int* order  = (int*)ip;                          // BB*OPB ints (640 KB)
    int* dgrp   = (int*)(ip + (size_t)BB * OPB * 4); // BB*GPB ints (40 KB)
    int* ntiles = (int*)(ip + (size_t)BB * (OPB + GPB) * 4);

    hipLaunchKernelGGL(k_sort16, dim3(BB), dim3(NN), 0, stream, e, order, dgrp, ntiles);

    hipLaunchKernelGGL(k_prep_a, dim3(TOTAL * 8 / 256), dim3(256), 0, stream, a, Ap);
    hipLaunchKernelGGL(k_prep_wt, dim3(HH, ND), dim3(64), 0, stream, W0, WT0, F_IN, 64);
    hipLaunchKernelGGL(k_prep_wt, dim3(HH, ND), dim3(64), 0, stream, W1, WT1, HH, HH);

    hipLaunchKernelGGL((k_conv_mfma<8>),  dim3(BB * TPB), dim3(256), 0, stream,
                       Ap, e, WT0, b0, order, dgrp, ntiles, xbuf);
    hipLaunchKernelGGL(k_pool_bf, dim3(TOTAL / 16), dim3(256), 0, stream, xbuf, e, pbuf);
    hipLaunchKernelGGL((k_conv_mfma<16>), dim3(BB * TPB), dim3(256), 0, stream,
                       pbuf, e, WT1, b1, order, dgrp, ntiles, xbuf);
    hipLaunchKernelGGL(k_pool_sum_part, dim3(BB * 8), dim3(256), 0, stream, xbuf, e, partial);
    hipLaunchKernelGGL(k_sum_final, dim3(BB * HH / 256), dim3(256), 0, stream, partial, out);
}